// Round 5
// baseline (454.887 us; speedup 1.0000x reference)
//
#include <hip/hip_runtime.h>
#include <math.h>

#define N_NODES 50000
#define N_EDGES 1000000
#define F_IN    165
#define HID     128
#define HEADS   4
#define F_OUT   32
#define NEG_SLOPE 0.2f
#define NB_SCAN  ((N_NODES + 255) / 256)   // 196 scan blocks

// ==== fused GEMM + attention logits ==========================================
// out[N,128] = X[N,K] @ W[K,128]; el/er[N,4] fused in epilogue.
// Block tile: 64 rows x 64 cols (2 complete heads); 256 threads; 4x4 per thread.
// K tiled by 32, double-buffered LDS xs[2][64][33] (16.9KB). Staging writes are
// stride-1; compute reads are 2-address wave-broadcasts (conflict-free).
template <int K>
__global__ __launch_bounds__(256) void gemm_fused(const float* __restrict__ X,
                                                  const float* __restrict__ W,
                                                  const float* __restrict__ al,
                                                  const float* __restrict__ ar,
                                                  float* __restrict__ out,
                                                  float* __restrict__ el,
                                                  float* __restrict__ er) {
    constexpr int KT = 32;
    constexpr int NKT = (K + KT - 1) / KT;
    __shared__ float xs[2][64][KT + 1];

    const int rb   = blockIdx.x >> 1;        // row block
    const int cb   = blockIdx.x & 1;         // col half (heads 0,1 / 2,3)
    const int base = rb * 64;
    const int co   = cb * 64;
    const int tid  = threadIdx.x;
    const int nrows = min(64, N_NODES - base);

    const int cg = tid & 15;                 // col group: 4 cols at c0
    const int rg = tid >> 4;                 // row group: 4 rows at r0
    const int c0 = cg * 4;
    const int r0 = rg * 4;
    const int hloc = cg >> 3;                // local head (0/1)
    const int h = cb * 2 + hloc;             // global head

    auto stage = [&](int buf, int t) {
        const int k0 = t * KT;
        const int cnt = min(KT, K - k0);
        for (int idx = tid; idx < 64 * KT; idx += 256) {
            const int r = idx >> 5;
            const int j = idx & 31;
            float v = 0.f;
            if (j < cnt && r < nrows) v = X[(size_t)(base + r) * K + k0 + j];
            xs[buf][r][j] = v;
        }
    };

    float acc[4][4];
#pragma unroll
    for (int i = 0; i < 4; ++i)
#pragma unroll
        for (int j = 0; j < 4; ++j) acc[i][j] = 0.f;

    stage(0, 0);
    __syncthreads();

    for (int t = 0; t < NKT; ++t) {
        const int buf = t & 1;
        if (t + 1 < NKT) stage(buf ^ 1, t + 1);
        const int k0 = t * KT;
        if (k0 + KT <= K) {
#pragma unroll
            for (int j = 0; j < KT; ++j) {
                const float4 wv = *(const float4*)&W[(size_t)(k0 + j) * HID + co + c0];
                float xr[4];
#pragma unroll
                for (int i = 0; i < 4; ++i) xr[i] = xs[buf][r0 + i][j];
#pragma unroll
                for (int i = 0; i < 4; ++i) {
                    acc[i][0] += xr[i] * wv.x;
                    acc[i][1] += xr[i] * wv.y;
                    acc[i][2] += xr[i] * wv.z;
                    acc[i][3] += xr[i] * wv.w;
                }
            }
        } else {
            for (int j = 0; j < K - k0; ++j) {
                const float4 wv = *(const float4*)&W[(size_t)(k0 + j) * HID + co + c0];
                float xr[4];
#pragma unroll
                for (int i = 0; i < 4; ++i) xr[i] = xs[buf][r0 + i][j];
#pragma unroll
                for (int i = 0; i < 4; ++i) {
                    acc[i][0] += xr[i] * wv.x;
                    acc[i][1] += xr[i] * wv.y;
                    acc[i][2] += xr[i] * wv.z;
                    acc[i][3] += xr[i] * wv.w;
                }
            }
        }
        __syncthreads();
    }

    // attention vectors for this thread's 4 cols
    const int f0 = (cg & 7) * 4;
    float alv[4], arv[4];
#pragma unroll
    for (int j = 0; j < 4; ++j) {
        alv[j] = al[h * F_OUT + f0 + j];
        arv[j] = ar[h * F_OUT + f0 + j];
    }

#pragma unroll
    for (int i = 0; i < 4; ++i) {
        const int node = base + r0 + i;
        float pl = acc[i][0] * alv[0] + acc[i][1] * alv[1] +
                   acc[i][2] * alv[2] + acc[i][3] * alv[3];
        float pr = acc[i][0] * arv[0] + acc[i][1] * arv[1] +
                   acc[i][2] * arv[2] + acc[i][3] * arv[3];
        pl += __shfl_xor(pl, 1); pr += __shfl_xor(pr, 1);
        pl += __shfl_xor(pl, 2); pr += __shfl_xor(pr, 2);
        pl += __shfl_xor(pl, 4); pr += __shfl_xor(pr, 4);
        if (r0 + i < nrows) {
            float4 o = make_float4(acc[i][0], acc[i][1], acc[i][2], acc[i][3]);
            *(float4*)&out[(size_t)node * HID + co + c0] = o;
            if ((cg & 7) == 0) {
                el[node * HEADS + h] = pl;
                er[node * HEADS + h] = pr;
            }
        }
    }
}

// ================= CSR build (once per launch, reused by both layers) ========

__global__ __launch_bounds__(256) void zero_counts(int* __restrict__ counts) {
    const int i = blockIdx.x * 256 + threadIdx.x;
    if (i < N_NODES) counts[i] = 0;
}

__global__ __launch_bounds__(256) void hist_dst(const int* __restrict__ dst,
                                                int* __restrict__ counts) {
    const int e = blockIdx.x * 256 + threadIdx.x;
    if (e < N_EDGES) atomicAdd(&counts[dst[e]], 1);
}

__global__ __launch_bounds__(256) void scan_local(const int* __restrict__ counts,
                                                  int* __restrict__ rowptr,
                                                  int* __restrict__ blockSums) {
    __shared__ int tmp[256];
    const int i = blockIdx.x * 256 + threadIdx.x;
    const int v = (i < N_NODES) ? counts[i] : 0;
    tmp[threadIdx.x] = v;
    __syncthreads();
#pragma unroll
    for (int off = 1; off < 256; off <<= 1) {
        int t = (threadIdx.x >= off) ? tmp[threadIdx.x - off] : 0;
        __syncthreads();
        tmp[threadIdx.x] += t;
        __syncthreads();
    }
    if (i < N_NODES) rowptr[i] = tmp[threadIdx.x] - v;
    if (threadIdx.x == 255) blockSums[blockIdx.x] = tmp[255];
}

__global__ __launch_bounds__(256) void scan_sums(int* __restrict__ blockSums) {
    __shared__ int tmp[256];
    const int v = (threadIdx.x < NB_SCAN) ? blockSums[threadIdx.x] : 0;
    tmp[threadIdx.x] = v;
    __syncthreads();
#pragma unroll
    for (int off = 1; off < 256; off <<= 1) {
        int t = (threadIdx.x >= off) ? tmp[threadIdx.x - off] : 0;
        __syncthreads();
        tmp[threadIdx.x] += t;
        __syncthreads();
    }
    if (threadIdx.x < NB_SCAN) blockSums[threadIdx.x] = tmp[threadIdx.x] - v;
}

__global__ __launch_bounds__(256) void add_offsets(int* __restrict__ rowptr,
                                                   const int* __restrict__ blockSums,
                                                   int* __restrict__ cursor) {
    const int i = blockIdx.x * 256 + threadIdx.x;
    if (i < N_NODES) {
        const int r = rowptr[i] + blockSums[blockIdx.x];
        rowptr[i] = r;
        cursor[i] = r;
    }
    if (i == 0) rowptr[N_NODES] = N_EDGES;
}

__global__ __launch_bounds__(256) void scatter_csr(const int* __restrict__ src,
                                                   const int* __restrict__ dst,
                                                   int* __restrict__ cursor,
                                                   int* __restrict__ csr_src) {
    const int e = blockIdx.x * 256 + threadIdx.x;
    if (e >= N_EDGES) return;
    const int pos = atomicAdd(&cursor[dst[e]], 1);
    csr_src[pos] = src[e];
}

// ===== fused GAT aggregation: single-pass exp-gather + normalize + ReLU ======
__global__ __launch_bounds__(256) void gat_aggregate(const int* __restrict__ rowptr,
                                                     const int* __restrict__ csr_src,
                                                     const float* __restrict__ el,
                                                     const float* __restrict__ er,
                                                     const float* __restrict__ feat,
                                                     float* __restrict__ outh) {
    const int d = (blockIdx.x * 256 + threadIdx.x) >> 6;
    if (d >= N_NODES) return;
    const int lane = threadIdx.x & 63;
    const int h = lane >> 4;
    const int start = rowptr[d], end = rowptr[d + 1];
    const float erd = er[d * HEADS + h];
    const float2* __restrict__ feat2 = (const float2*)feat;

    float denom = 0.f, ax = 0.f, ay = 0.f;
    for (int chunk = start; chunk < end; chunk += 64) {
        const int cnt = min(64, end - chunk);
        const int idx = chunk + lane;
        const int sv = csr_src[idx < end ? idx : start];
        int i = 0;
        for (; i + 2 <= cnt; i += 2) {
            const int s0 = __shfl(sv, i);
            const int s1 = __shfl(sv, i + 1);
            const float e0 = el[s0 * HEADS + h];
            const float e1 = el[s1 * HEADS + h];
            const float2 f0 = feat2[(size_t)s0 * 64 + lane];
            const float2 f1 = feat2[(size_t)s1 * 64 + lane];
            float v0 = e0 + erd; v0 = v0 > 0.f ? v0 : NEG_SLOPE * v0;
            float v1 = e1 + erd; v1 = v1 > 0.f ? v1 : NEG_SLOPE * v1;
            const float x0 = __expf(v0);
            const float x1 = __expf(v1);
            denom += x0 + x1;
            ax += f0.x * x0 + f1.x * x1;
            ay += f0.y * x0 + f1.y * x1;
        }
        if (i < cnt) {
            const int s0 = __shfl(sv, i);
            const float e0 = el[s0 * HEADS + h];
            const float2 f0 = feat2[(size_t)s0 * 64 + lane];
            float v0 = e0 + erd; v0 = v0 > 0.f ? v0 : NEG_SLOPE * v0;
            const float x0 = __expf(v0);
            denom += x0;
            ax += f0.x * x0;
            ay += f0.y * x0;
        }
    }
    const float inv = 1.f / fmaxf(denom, 1e-9f);
    float2 r;
    r.x = fmaxf(ax * inv, 0.f);
    r.y = fmaxf(ay * inv, 0.f);
    *(float2*)&outh[(size_t)d * HID + lane * 2] = r;
}

// ---- MLP heads: wave per node ----
__global__ __launch_bounds__(256) void heads_kernel(const float* __restrict__ hbuf,
                                                    const float* __restrict__ Wc1,
                                                    const float* __restrict__ bc1,
                                                    const float* __restrict__ Wc2,
                                                    const float* __restrict__ bc2,
                                                    const float* __restrict__ Wf1,
                                                    const float* __restrict__ bf1,
                                                    const float* __restrict__ Wf2,
                                                    const float* __restrict__ bf2,
                                                    float* __restrict__ out) {
    const int wid = (blockIdx.x * 256 + threadIdx.x) >> 6;
    if (wid >= N_NODES) return;
    const int lane = threadIdx.x & 63;
    float2 x = *(const float2*)&hbuf[wid * HID + lane * 2];
    float ac[10], af[10];
#pragma unroll
    for (int o = 0; o < 10; ++o) {
        ac[o] = x.x * Wc1[(lane * 2) * 10 + o] + x.y * Wc1[(lane * 2 + 1) * 10 + o];
        af[o] = x.x * Wf1[(lane * 2) * 10 + o] + x.y * Wf1[(lane * 2 + 1) * 10 + o];
    }
#pragma unroll
    for (int off = 32; off >= 1; off >>= 1) {
#pragma unroll
        for (int o = 0; o < 10; ++o) {
            ac[o] += __shfl_xor(ac[o], off);
            af[o] += __shfl_xor(af[o], off);
        }
    }
    if (lane == 0) {
        float pc = bc2[0], pf = bf2[0];
#pragma unroll
        for (int o = 0; o < 10; ++o) {
            pc += fmaxf(ac[o] + bc1[o], 0.f) * Wc2[o];
            pf += fmaxf(af[o] + bf1[o], 0.f) * Wf2[o];
        }
        out[wid] = pc;
        out[N_NODES + wid] = 1.0f / (1.0f + __expf(-pf));
    }
}

extern "C" void kernel_launch(void* const* d_in, const int* in_sizes, int n_in,
                              void* d_out, int out_size, void* d_ws, size_t ws_size,
                              hipStream_t stream) {
    const float* features = (const float*)d_in[0];
    const int*   src      = (const int*)d_in[1];
    const int*   dst      = (const int*)d_in[2];
    const float* W1  = (const float*)d_in[3];
    const float* al1 = (const float*)d_in[4];
    const float* ar1 = (const float*)d_in[5];
    const float* W2  = (const float*)d_in[6];
    const float* al2 = (const float*)d_in[7];
    const float* ar2 = (const float*)d_in[8];
    const float* Wc1 = (const float*)d_in[9];
    const float* bc1 = (const float*)d_in[10];
    const float* Wc2 = (const float*)d_in[11];
    const float* bc2 = (const float*)d_in[12];
    const float* Wf1 = (const float*)d_in[13];
    const float* bf1 = (const float*)d_in[14];
    const float* Wf2 = (const float*)d_in[15];
    const float* bf2 = (const float*)d_in[16];
    float* out = (float*)d_out;

    // workspace layout:
    // floats: feat[128N] | hbuf[128N] | el[4N] | er[4N]
    // ints:   counts[N] | rowptr[N+1] | cursor[N] | blockSums[256] | csr_src[E]
    float* feat = (float*)d_ws;
    float* hbuf = feat + (size_t)N_NODES * HID;
    float* el   = hbuf + (size_t)N_NODES * HID;
    float* er   = el + (size_t)N_NODES * HEADS;
    int* counts    = (int*)(er + (size_t)N_NODES * HEADS);
    int* rowptr    = counts + N_NODES;
    int* cursor    = rowptr + N_NODES + 1;
    int* blockSums = cursor + N_NODES;
    int* csr_src   = blockSums + 256;

    const int nodeWaveBlocks = (N_NODES * 64 + 255) / 256;   // 12500
    const int edgeBlocks     = (N_EDGES + 255) / 256;        // 3907
    const int gemmBlocks     = ((N_NODES + 63) / 64) * 2;    // 1564

    // ---------- CSR build (dst-sorted incidence), reused by both layers ------
    zero_counts<<<NB_SCAN, 256, 0, stream>>>(counts);
    hist_dst<<<edgeBlocks, 256, 0, stream>>>(dst, counts);
    scan_local<<<NB_SCAN, 256, 0, stream>>>(counts, rowptr, blockSums);
    scan_sums<<<1, 256, 0, stream>>>(blockSums);
    add_offsets<<<NB_SCAN, 256, 0, stream>>>(rowptr, blockSums, cursor);
    scatter_csr<<<edgeBlocks, 256, 0, stream>>>(src, dst, cursor, csr_src);

    // ---------- layer 1 ----------
    gemm_fused<F_IN><<<gemmBlocks, 256, 0, stream>>>(features, W1, al1, ar1,
                                                     feat, el, er);
    gat_aggregate<<<nodeWaveBlocks, 256, 0, stream>>>(rowptr, csr_src, el, er, feat, hbuf);

    // ---------- layer 2 ----------
    gemm_fused<HID><<<gemmBlocks, 256, 0, stream>>>(hbuf, W2, al2, ar2,
                                                    feat, el, er);
    gat_aggregate<<<nodeWaveBlocks, 256, 0, stream>>>(rowptr, csr_src, el, er, feat, hbuf);

    // ---------- heads ----------
    heads_kernel<<<nodeWaveBlocks, 256, 0, stream>>>(hbuf, Wc1, bc1, Wc2, bc2,
                                                     Wf1, bf1, Wf2, bf2, out);
}

// Round 6
// 415.725 us; speedup vs baseline: 1.0942x; 1.0942x over previous
//
#include <hip/hip_runtime.h>
#include <math.h>

#define N_NODES 50000
#define N_EDGES 1000000
#define F_IN    165
#define HID     128
#define HEADS   4
#define F_OUT   32
#define NEG_SLOPE 0.2f
#define NB_SCAN  ((N_NODES + 255) / 256)   // 196 scan blocks

// ==== fused GEMM + attention logits ==========================================
// out[N,128] = X[N,K] @ W[K,128]; el/er[N,4] fused in epilogue.
// Block tile: 64 rows x 64 cols (2 heads); 256 threads; 4x4 per thread.
// K tiled by 32. Single LDS buffer, k-major transposed xs[j][r] (stride 68,
// 8.7KB); compute reads are one ds_read_b128 per k-step (conflict-free:
// 4 distinct addresses/wave + 16-way broadcast). T14 async-STAGE split:
// next tile loaded to REGISTERS before compute, ds_write after barrier, so
// the vmcnt wait is covered by 32x16 FMAs.
template <int K>
__global__ __launch_bounds__(256) void gemm_fused(const float* __restrict__ X,
                                                  const float* __restrict__ W,
                                                  const float* __restrict__ al,
                                                  const float* __restrict__ ar,
                                                  float* __restrict__ out,
                                                  float* __restrict__ el,
                                                  float* __restrict__ er) {
    constexpr int KT = 32;
    constexpr int NKT = (K + KT - 1) / KT;
    constexpr int LDR = 68;                 // row stride (floats), 16B-aligned
    __shared__ float xs[KT * LDR];          // xs[j*LDR + r] = X[base+r][k0+j]

    const int rb   = blockIdx.x >> 1;
    const int cb   = blockIdx.x & 1;
    const int base = rb * 64;
    const int co   = cb * 64;
    const int tid  = threadIdx.x;
    const int nrows = min(64, N_NODES - base);

    const int cg = tid & 15;                // col group: 4 cols at c0
    const int rg = tid >> 4;                // row group: 4 rows at r0
    const int c0 = cg * 4;
    const int r0 = rg * 4;
    const int hloc = cg >> 3;
    const int h = cb * 2 + hloc;

    const int sr = tid >> 5;                // staging row base (0..7)
    const int sj = tid & 31;                // staging k offset (0..31)

    float stg[8];
    // ---- load + write tile 0 ----
#pragma unroll
    for (int s = 0; s < 8; ++s) {
        const int r = sr + 8 * s;
        stg[s] = (r < nrows && sj < K) ? X[(size_t)(base + r) * K + sj] : 0.f;
    }
#pragma unroll
    for (int s = 0; s < 8; ++s) xs[sj * LDR + sr + 8 * s] = stg[s];
    __syncthreads();

    float acc[4][4];
#pragma unroll
    for (int i = 0; i < 4; ++i)
#pragma unroll
        for (int j = 0; j < 4; ++j) acc[i][j] = 0.f;

    for (int t = 0; t < NKT; ++t) {
        const int k0 = t * KT;
        // prefetch next tile into registers (no wait until the ds_write below)
        if (t + 1 < NKT) {
            const int nk0 = k0 + KT;
#pragma unroll
            for (int s = 0; s < 8; ++s) {
                const int r = sr + 8 * s;
                stg[s] = (r < nrows && nk0 + sj < K)
                             ? X[(size_t)(base + r) * K + nk0 + sj] : 0.f;
            }
        }
        // compute on current tile
        const int cnt = min(KT, K - k0);
        if (cnt == KT) {
#pragma unroll
            for (int j = 0; j < KT; ++j) {
                const float4 wv = *(const float4*)&W[(size_t)(k0 + j) * HID + co + c0];
                const float4 xr = *(const float4*)&xs[j * LDR + r0];
                acc[0][0] += xr.x * wv.x; acc[0][1] += xr.x * wv.y;
                acc[0][2] += xr.x * wv.z; acc[0][3] += xr.x * wv.w;
                acc[1][0] += xr.y * wv.x; acc[1][1] += xr.y * wv.y;
                acc[1][2] += xr.y * wv.z; acc[1][3] += xr.y * wv.w;
                acc[2][0] += xr.z * wv.x; acc[2][1] += xr.z * wv.y;
                acc[2][2] += xr.z * wv.z; acc[2][3] += xr.z * wv.w;
                acc[3][0] += xr.w * wv.x; acc[3][1] += xr.w * wv.y;
                acc[3][2] += xr.w * wv.z; acc[3][3] += xr.w * wv.w;
            }
        } else {
            for (int j = 0; j < cnt; ++j) {
                const float4 wv = *(const float4*)&W[(size_t)(k0 + j) * HID + co + c0];
                const float4 xr = *(const float4*)&xs[j * LDR + r0];
                acc[0][0] += xr.x * wv.x; acc[0][1] += xr.x * wv.y;
                acc[0][2] += xr.x * wv.z; acc[0][3] += xr.x * wv.w;
                acc[1][0] += xr.y * wv.x; acc[1][1] += xr.y * wv.y;
                acc[1][2] += xr.y * wv.z; acc[1][3] += xr.y * wv.w;
                acc[2][0] += xr.z * wv.x; acc[2][1] += xr.z * wv.y;
                acc[2][2] += xr.z * wv.z; acc[2][3] += xr.z * wv.w;
                acc[3][0] += xr.w * wv.x; acc[3][1] += xr.w * wv.y;
                acc[3][2] += xr.w * wv.z; acc[3][3] += xr.w * wv.w;
            }
        }
        if (t + 1 < NKT) {
            __syncthreads();   // everyone done reading xs
#pragma unroll
            for (int s = 0; s < 8; ++s) xs[sj * LDR + sr + 8 * s] = stg[s];
            __syncthreads();   // tile t+1 visible
        }
    }

    // attention vectors for this thread's 4 cols
    const int f0 = (cg & 7) * 4;
    float alv[4], arv[4];
#pragma unroll
    for (int j = 0; j < 4; ++j) {
        alv[j] = al[h * F_OUT + f0 + j];
        arv[j] = ar[h * F_OUT + f0 + j];
    }

#pragma unroll
    for (int i = 0; i < 4; ++i) {
        const int node = base + r0 + i;
        float pl = acc[i][0] * alv[0] + acc[i][1] * alv[1] +
                   acc[i][2] * alv[2] + acc[i][3] * alv[3];
        float pr = acc[i][0] * arv[0] + acc[i][1] * arv[1] +
                   acc[i][2] * arv[2] + acc[i][3] * arv[3];
        pl += __shfl_xor(pl, 1); pr += __shfl_xor(pr, 1);
        pl += __shfl_xor(pl, 2); pr += __shfl_xor(pr, 2);
        pl += __shfl_xor(pl, 4); pr += __shfl_xor(pr, 4);
        if (r0 + i < nrows) {
            float4 o = make_float4(acc[i][0], acc[i][1], acc[i][2], acc[i][3]);
            *(float4*)&out[(size_t)node * HID + co + c0] = o;
            if ((cg & 7) == 0) {
                el[node * HEADS + h] = pl;
                er[node * HEADS + h] = pr;
            }
        }
    }
}

// ================= CSR build (once per launch, reused by both layers) ========

__global__ __launch_bounds__(256) void zero_counts(int* __restrict__ counts) {
    const int i = blockIdx.x * 256 + threadIdx.x;
    if (i < N_NODES) counts[i] = 0;
}

__global__ __launch_bounds__(256) void hist_dst(const int* __restrict__ dst,
                                                int* __restrict__ counts) {
    const int e = blockIdx.x * 256 + threadIdx.x;
    if (e < N_EDGES) atomicAdd(&counts[dst[e]], 1);
}

__global__ __launch_bounds__(256) void scan_local(const int* __restrict__ counts,
                                                  int* __restrict__ rowptr,
                                                  int* __restrict__ blockSums) {
    __shared__ int tmp[256];
    const int i = blockIdx.x * 256 + threadIdx.x;
    const int v = (i < N_NODES) ? counts[i] : 0;
    tmp[threadIdx.x] = v;
    __syncthreads();
#pragma unroll
    for (int off = 1; off < 256; off <<= 1) {
        int t = (threadIdx.x >= off) ? tmp[threadIdx.x - off] : 0;
        __syncthreads();
        tmp[threadIdx.x] += t;
        __syncthreads();
    }
    if (i < N_NODES) rowptr[i] = tmp[threadIdx.x] - v;
    if (threadIdx.x == 255) blockSums[blockIdx.x] = tmp[255];
}

__global__ __launch_bounds__(256) void scan_sums(int* __restrict__ blockSums) {
    __shared__ int tmp[256];
    const int v = (threadIdx.x < NB_SCAN) ? blockSums[threadIdx.x] : 0;
    tmp[threadIdx.x] = v;
    __syncthreads();
#pragma unroll
    for (int off = 1; off < 256; off <<= 1) {
        int t = (threadIdx.x >= off) ? tmp[threadIdx.x - off] : 0;
        __syncthreads();
        tmp[threadIdx.x] += t;
        __syncthreads();
    }
    if (threadIdx.x < NB_SCAN) blockSums[threadIdx.x] = tmp[threadIdx.x] - v;
}

__global__ __launch_bounds__(256) void add_offsets(int* __restrict__ rowptr,
                                                   const int* __restrict__ blockSums,
                                                   int* __restrict__ cursor) {
    const int i = blockIdx.x * 256 + threadIdx.x;
    if (i < N_NODES) {
        const int r = rowptr[i] + blockSums[blockIdx.x];
        rowptr[i] = r;
        cursor[i] = r;
    }
    if (i == 0) rowptr[N_NODES] = N_EDGES;
}

__global__ __launch_bounds__(256) void scatter_csr(const int* __restrict__ src,
                                                   const int* __restrict__ dst,
                                                   int* __restrict__ cursor,
                                                   int* __restrict__ csr_src) {
    const int e = blockIdx.x * 256 + threadIdx.x;
    if (e >= N_EDGES) return;
    const int pos = atomicAdd(&cursor[dst[e]], 1);
    csr_src[pos] = src[e];
}

// ===== fused GAT aggregation: single-pass exp-gather + normalize + ReLU ======
// FUSE_HEADS: layer-2 variant additionally computes both MLP heads from the
// in-register h2 and writes predict/confidence directly (no hbuf round-trip).
template <bool FUSE_HEADS>
__global__ __launch_bounds__(256) void gat_aggregate(const int* __restrict__ rowptr,
                                                     const int* __restrict__ csr_src,
                                                     const float* __restrict__ el,
                                                     const float* __restrict__ er,
                                                     const float* __restrict__ feat,
                                                     float* __restrict__ outh,
                                                     const float* __restrict__ Wc1,
                                                     const float* __restrict__ bc1,
                                                     const float* __restrict__ Wc2,
                                                     const float* __restrict__ bc2,
                                                     const float* __restrict__ Wf1,
                                                     const float* __restrict__ bf1,
                                                     const float* __restrict__ Wf2,
                                                     const float* __restrict__ bf2,
                                                     float* __restrict__ out) {
    const int d = (blockIdx.x * 256 + threadIdx.x) >> 6;
    if (d >= N_NODES) return;
    const int lane = threadIdx.x & 63;
    const int h = lane >> 4;
    const int start = rowptr[d], end = rowptr[d + 1];
    const float erd = er[d * HEADS + h];
    const float2* __restrict__ feat2 = (const float2*)feat;

    float denom = 0.f, ax = 0.f, ay = 0.f;
    for (int chunk = start; chunk < end; chunk += 64) {
        const int cnt = min(64, end - chunk);
        const int idx = chunk + lane;
        const int sv = csr_src[idx < end ? idx : start];
        int i = 0;
        for (; i + 2 <= cnt; i += 2) {
            const int s0 = __shfl(sv, i);
            const int s1 = __shfl(sv, i + 1);
            const float e0 = el[s0 * HEADS + h];
            const float e1 = el[s1 * HEADS + h];
            const float2 f0 = feat2[(size_t)s0 * 64 + lane];
            const float2 f1 = feat2[(size_t)s1 * 64 + lane];
            float v0 = e0 + erd; v0 = v0 > 0.f ? v0 : NEG_SLOPE * v0;
            float v1 = e1 + erd; v1 = v1 > 0.f ? v1 : NEG_SLOPE * v1;
            const float x0 = __expf(v0);
            const float x1 = __expf(v1);
            denom += x0 + x1;
            ax += f0.x * x0 + f1.x * x1;
            ay += f0.y * x0 + f1.y * x1;
        }
        if (i < cnt) {
            const int s0 = __shfl(sv, i);
            const float e0 = el[s0 * HEADS + h];
            const float2 f0 = feat2[(size_t)s0 * 64 + lane];
            float v0 = e0 + erd; v0 = v0 > 0.f ? v0 : NEG_SLOPE * v0;
            const float x0 = __expf(v0);
            denom += x0;
            ax += f0.x * x0;
            ay += f0.y * x0;
        }
    }
    const float inv = 1.f / fmaxf(denom, 1e-9f);
    const float hx = fmaxf(ax * inv, 0.f);
    const float hy = fmaxf(ay * inv, 0.f);

    if (!FUSE_HEADS) {
        *(float2*)&outh[(size_t)d * HID + lane * 2] = make_float2(hx, hy);
        return;
    }

    // ---- fused MLP heads on in-register h2 ----
    float ac[10], af[10];
#pragma unroll
    for (int o = 0; o < 10; ++o) {
        ac[o] = hx * Wc1[(lane * 2) * 10 + o] + hy * Wc1[(lane * 2 + 1) * 10 + o];
        af[o] = hx * Wf1[(lane * 2) * 10 + o] + hy * Wf1[(lane * 2 + 1) * 10 + o];
    }
#pragma unroll
    for (int off = 32; off >= 1; off >>= 1) {
#pragma unroll
        for (int o = 0; o < 10; ++o) {
            ac[o] += __shfl_xor(ac[o], off);
            af[o] += __shfl_xor(af[o], off);
        }
    }
    if (lane == 0) {
        float pc = bc2[0], pf = bf2[0];
#pragma unroll
        for (int o = 0; o < 10; ++o) {
            pc += fmaxf(ac[o] + bc1[o], 0.f) * Wc2[o];
            pf += fmaxf(af[o] + bf1[o], 0.f) * Wf2[o];
        }
        out[d] = pc;
        out[N_NODES + d] = 1.0f / (1.0f + __expf(-pf));
    }
}

extern "C" void kernel_launch(void* const* d_in, const int* in_sizes, int n_in,
                              void* d_out, int out_size, void* d_ws, size_t ws_size,
                              hipStream_t stream) {
    const float* features = (const float*)d_in[0];
    const int*   src      = (const int*)d_in[1];
    const int*   dst      = (const int*)d_in[2];
    const float* W1  = (const float*)d_in[3];
    const float* al1 = (const float*)d_in[4];
    const float* ar1 = (const float*)d_in[5];
    const float* W2  = (const float*)d_in[6];
    const float* al2 = (const float*)d_in[7];
    const float* ar2 = (const float*)d_in[8];
    const float* Wc1 = (const float*)d_in[9];
    const float* bc1 = (const float*)d_in[10];
    const float* Wc2 = (const float*)d_in[11];
    const float* bc2 = (const float*)d_in[12];
    const float* Wf1 = (const float*)d_in[13];
    const float* bf1 = (const float*)d_in[14];
    const float* Wf2 = (const float*)d_in[15];
    const float* bf2 = (const float*)d_in[16];
    float* out = (float*)d_out;

    // workspace layout:
    // floats: feat[128N] | hbuf[128N] | el[4N] | er[4N]
    // ints:   counts[N] | rowptr[N+1] | cursor[N] | blockSums[256] | csr_src[E]
    float* feat = (float*)d_ws;
    float* hbuf = feat + (size_t)N_NODES * HID;
    float* el   = hbuf + (size_t)N_NODES * HID;
    float* er   = el + (size_t)N_NODES * HEADS;
    int* counts    = (int*)(er + (size_t)N_NODES * HEADS);
    int* rowptr    = counts + N_NODES;
    int* cursor    = rowptr + N_NODES + 1;
    int* blockSums = cursor + N_NODES;
    int* csr_src   = blockSums + 256;

    const int nodeWaveBlocks = (N_NODES * 64 + 255) / 256;   // 12500
    const int edgeBlocks     = (N_EDGES + 255) / 256;        // 3907
    const int gemmBlocks     = ((N_NODES + 63) / 64) * 2;    // 1564

    // ---------- CSR build (dst-sorted incidence), reused by both layers ------
    zero_counts<<<NB_SCAN, 256, 0, stream>>>(counts);
    hist_dst<<<edgeBlocks, 256, 0, stream>>>(dst, counts);
    scan_local<<<NB_SCAN, 256, 0, stream>>>(counts, rowptr, blockSums);
    scan_sums<<<1, 256, 0, stream>>>(blockSums);
    add_offsets<<<NB_SCAN, 256, 0, stream>>>(rowptr, blockSums, cursor);
    scatter_csr<<<edgeBlocks, 256, 0, stream>>>(src, dst, cursor, csr_src);

    // ---------- layer 1 ----------
    gemm_fused<F_IN><<<gemmBlocks, 256, 0, stream>>>(features, W1, al1, ar1,
                                                     feat, el, er);
    gat_aggregate<false><<<nodeWaveBlocks, 256, 0, stream>>>(
        rowptr, csr_src, el, er, feat, hbuf,
        Wc1, bc1, Wc2, bc2, Wf1, bf1, Wf2, bf2, out);

    // ---------- layer 2 (heads fused into aggregation epilogue) ----------
    gemm_fused<HID><<<gemmBlocks, 256, 0, stream>>>(hbuf, W2, al2, ar2,
                                                    feat, el, er);
    gat_aggregate<true><<<nodeWaveBlocks, 256, 0, stream>>>(
        rowptr, csr_src, el, er, feat, nullptr,
        Wc1, bc1, Wc2, bc2, Wf1, bf1, Wf2, bf2, out);
}

// Round 7
// 349.130 us; speedup vs baseline: 1.3029x; 1.1907x over previous
//
#include <hip/hip_runtime.h>
#include <hip/hip_fp16.h>
#include <math.h>

#define N_NODES 50000
#define N_EDGES 1000000
#define F_IN    165
#define HID     128
#define HEADS   4
#define F_OUT   32
#define NEG_SLOPE 0.2f
#define NB_SCAN  ((N_NODES + 255) / 256)   // 196 scan blocks
#define NPART    8                          // dst partitions (= XCDs)
#define PART_SZ  (N_NODES / NPART)          // 6250, exact
#define SCHUNKS  256                        // edge chunks for scatter

// ==== fused GEMM + attention logits ==========================================
// out[N,128] = X[N,K] @ W[K,128] stored as fp16; el/er[N,4] fp32 in epilogue.
// Block tile: 64 rows x 64 cols (2 heads); 256 threads; 4x4 per thread.
// K tiled by 32, single LDS buffer k-major xs[j][r] (stride 68, 8.7KB).
// T14 async-STAGE: next tile -> registers before compute, ds_write after
// barrier, so the vmcnt wait is covered by 32x16 FMAs.
template <int K>
__global__ __launch_bounds__(256) void gemm_fused(const float* __restrict__ X,
                                                  const float* __restrict__ W,
                                                  const float* __restrict__ al,
                                                  const float* __restrict__ ar,
                                                  __half* __restrict__ feat,
                                                  float* __restrict__ el,
                                                  float* __restrict__ er) {
    constexpr int KT = 32;
    constexpr int NKT = (K + KT - 1) / KT;
    constexpr int LDR = 68;
    __shared__ float xs[KT * LDR];          // xs[j*LDR + r] = X[base+r][k0+j]

    const int rb   = blockIdx.x >> 1;
    const int cb   = blockIdx.x & 1;
    const int base = rb * 64;
    const int co   = cb * 64;
    const int tid  = threadIdx.x;
    const int nrows = min(64, N_NODES - base);

    const int cg = tid & 15;                // col group: 4 cols at c0
    const int rg = tid >> 4;                // row group: 4 rows at r0
    const int c0 = cg * 4;
    const int r0 = rg * 4;
    const int hloc = cg >> 3;
    const int h = cb * 2 + hloc;

    const int sr = tid >> 5;                // staging row base (0..7)
    const int sj = tid & 31;                // staging k offset (0..31)

    float stg[8];
#pragma unroll
    for (int s = 0; s < 8; ++s) {
        const int r = sr + 8 * s;
        stg[s] = (r < nrows && sj < K) ? X[(size_t)(base + r) * K + sj] : 0.f;
    }
#pragma unroll
    for (int s = 0; s < 8; ++s) xs[sj * LDR + sr + 8 * s] = stg[s];
    __syncthreads();

    float acc[4][4];
#pragma unroll
    for (int i = 0; i < 4; ++i)
#pragma unroll
        for (int j = 0; j < 4; ++j) acc[i][j] = 0.f;

    for (int t = 0; t < NKT; ++t) {
        const int k0 = t * KT;
        if (t + 1 < NKT) {
            const int nk0 = k0 + KT;
#pragma unroll
            for (int s = 0; s < 8; ++s) {
                const int r = sr + 8 * s;
                stg[s] = (r < nrows && nk0 + sj < K)
                             ? X[(size_t)(base + r) * K + nk0 + sj] : 0.f;
            }
        }
        const int cnt = min(KT, K - k0);
        if (cnt == KT) {
#pragma unroll
            for (int j = 0; j < KT; ++j) {
                const float4 wv = *(const float4*)&W[(size_t)(k0 + j) * HID + co + c0];
                const float4 xr = *(const float4*)&xs[j * LDR + r0];
                acc[0][0] += xr.x * wv.x; acc[0][1] += xr.x * wv.y;
                acc[0][2] += xr.x * wv.z; acc[0][3] += xr.x * wv.w;
                acc[1][0] += xr.y * wv.x; acc[1][1] += xr.y * wv.y;
                acc[1][2] += xr.y * wv.z; acc[1][3] += xr.y * wv.w;
                acc[2][0] += xr.z * wv.x; acc[2][1] += xr.z * wv.y;
                acc[2][2] += xr.z * wv.z; acc[2][3] += xr.z * wv.w;
                acc[3][0] += xr.w * wv.x; acc[3][1] += xr.w * wv.y;
                acc[3][2] += xr.w * wv.z; acc[3][3] += xr.w * wv.w;
            }
        } else {
            for (int j = 0; j < cnt; ++j) {
                const float4 wv = *(const float4*)&W[(size_t)(k0 + j) * HID + co + c0];
                const float4 xr = *(const float4*)&xs[j * LDR + r0];
                acc[0][0] += xr.x * wv.x; acc[0][1] += xr.x * wv.y;
                acc[0][2] += xr.x * wv.z; acc[0][3] += xr.x * wv.w;
                acc[1][0] += xr.y * wv.x; acc[1][1] += xr.y * wv.y;
                acc[1][2] += xr.y * wv.z; acc[1][3] += xr.y * wv.w;
                acc[2][0] += xr.z * wv.x; acc[2][1] += xr.z * wv.y;
                acc[2][2] += xr.z * wv.z; acc[2][3] += xr.z * wv.w;
                acc[3][0] += xr.w * wv.x; acc[3][1] += xr.w * wv.y;
                acc[3][2] += xr.w * wv.z; acc[3][3] += xr.w * wv.w;
            }
        }
        if (t + 1 < NKT) {
            __syncthreads();
#pragma unroll
            for (int s = 0; s < 8; ++s) xs[sj * LDR + sr + 8 * s] = stg[s];
            __syncthreads();
        }
    }

    const int f0 = (cg & 7) * 4;
    float alv[4], arv[4];
#pragma unroll
    for (int j = 0; j < 4; ++j) {
        alv[j] = al[h * F_OUT + f0 + j];
        arv[j] = ar[h * F_OUT + f0 + j];
    }

#pragma unroll
    for (int i = 0; i < 4; ++i) {
        const int node = base + r0 + i;
        float pl = acc[i][0] * alv[0] + acc[i][1] * alv[1] +
                   acc[i][2] * alv[2] + acc[i][3] * alv[3];
        float pr = acc[i][0] * arv[0] + acc[i][1] * arv[1] +
                   acc[i][2] * arv[2] + acc[i][3] * arv[3];
        pl += __shfl_xor(pl, 1); pr += __shfl_xor(pr, 1);
        pl += __shfl_xor(pl, 2); pr += __shfl_xor(pr, 2);
        pl += __shfl_xor(pl, 4); pr += __shfl_xor(pr, 4);
        if (r0 + i < nrows) {
            const __half2 p0 = __floats2half2_rn(acc[i][0], acc[i][1]);
            const __half2 p1 = __floats2half2_rn(acc[i][2], acc[i][3]);
            uint2 u;
            u.x = *(const unsigned int*)&p0;
            u.y = *(const unsigned int*)&p1;
            *(uint2*)&feat[(size_t)node * HID + co + c0] = u;
            if ((cg & 7) == 0) {
                el[node * HEADS + h] = pl;
                er[node * HEADS + h] = pr;
            }
        }
    }
}

// ================= CSR build (once per launch, reused by both layers) ========

__global__ __launch_bounds__(256) void zero_counts(int* __restrict__ counts) {
    const int i = blockIdx.x * 256 + threadIdx.x;
    if (i < N_NODES) counts[i] = 0;
}

__global__ __launch_bounds__(256) void hist_dst(const int* __restrict__ dst,
                                                int* __restrict__ counts) {
    const int e = blockIdx.x * 256 + threadIdx.x;
    if (e < N_EDGES) atomicAdd(&counts[dst[e]], 1);
}

__global__ __launch_bounds__(256) void scan_local(const int* __restrict__ counts,
                                                  int* __restrict__ rowptr,
                                                  int* __restrict__ blockSums) {
    __shared__ int tmp[256];
    const int i = blockIdx.x * 256 + threadIdx.x;
    const int v = (i < N_NODES) ? counts[i] : 0;
    tmp[threadIdx.x] = v;
    __syncthreads();
#pragma unroll
    for (int off = 1; off < 256; off <<= 1) {
        int t = (threadIdx.x >= off) ? tmp[threadIdx.x - off] : 0;
        __syncthreads();
        tmp[threadIdx.x] += t;
        __syncthreads();
    }
    if (i < N_NODES) rowptr[i] = tmp[threadIdx.x] - v;
    if (threadIdx.x == 255) blockSums[blockIdx.x] = tmp[255];
}

__global__ __launch_bounds__(256) void scan_sums(int* __restrict__ blockSums) {
    __shared__ int tmp[256];
    const int v = (threadIdx.x < NB_SCAN) ? blockSums[threadIdx.x] : 0;
    tmp[threadIdx.x] = v;
    __syncthreads();
#pragma unroll
    for (int off = 1; off < 256; off <<= 1) {
        int t = (threadIdx.x >= off) ? tmp[threadIdx.x - off] : 0;
        __syncthreads();
        tmp[threadIdx.x] += t;
        __syncthreads();
    }
    if (threadIdx.x < NB_SCAN) blockSums[threadIdx.x] = tmp[threadIdx.x] - v;
}

__global__ __launch_bounds__(256) void add_offsets(int* __restrict__ rowptr,
                                                   const int* __restrict__ blockSums,
                                                   int* __restrict__ cursor) {
    const int i = blockIdx.x * 256 + threadIdx.x;
    if (i < N_NODES) {
        const int r = rowptr[i] + blockSums[blockIdx.x];
        rowptr[i] = r;
        cursor[i] = r;
    }
    if (i == 0) rowptr[N_NODES] = N_EDGES;
}

// XCD-partitioned scatter: partition p = blockIdx&7 owns dst range
// [p*6250, (p+1)*6250). Under round-robin block->XCD dispatch all writers of a
// csr_src line sit on one XCD -> line accumulates in local L2 (write traffic
// ~4MB instead of 67MB of cross-XCD line ping-pong). Correctness does not
// depend on the dispatch mapping.
__global__ __launch_bounds__(256) void scatter_csr_part(const int* __restrict__ src,
                                                        const int* __restrict__ dst,
                                                        int* __restrict__ cursor,
                                                        int* __restrict__ csr_src) {
    const int part  = blockIdx.x & (NPART - 1);
    const int chunk = blockIdx.x >> 3;
    constexpr int CE = (N_EDGES + SCHUNKS - 1) / SCHUNKS;   // 3907
    const int e0 = chunk * CE;
    const int e1 = min(e0 + CE, N_EDGES);
    for (int e = e0 + threadIdx.x; e < e1; e += 256) {
        const int d = dst[e];
        if (d / PART_SZ == part) {
            const int pos = atomicAdd(&cursor[d], 1);
            csr_src[pos] = src[e];
        }
    }
}

// ===== fused GAT aggregation: single-pass exp-gather + normalize + ReLU ======
// feat is fp16 (halves gather traffic); math fp32. Edge loop unrolled x4.
// FUSE_HEADS: layer-2 variant computes both MLP heads from in-register h2.
template <bool FUSE_HEADS>
__global__ __launch_bounds__(256) void gat_aggregate(const int* __restrict__ rowptr,
                                                     const int* __restrict__ csr_src,
                                                     const float* __restrict__ el,
                                                     const float* __restrict__ er,
                                                     const __half* __restrict__ feat,
                                                     float* __restrict__ outh,
                                                     const float* __restrict__ Wc1,
                                                     const float* __restrict__ bc1,
                                                     const float* __restrict__ Wc2,
                                                     const float* __restrict__ bc2,
                                                     const float* __restrict__ Wf1,
                                                     const float* __restrict__ bf1,
                                                     const float* __restrict__ Wf2,
                                                     const float* __restrict__ bf2,
                                                     float* __restrict__ out) {
    const int d = (blockIdx.x * 256 + threadIdx.x) >> 6;
    if (d >= N_NODES) return;
    const int lane = threadIdx.x & 63;
    const int h = lane >> 4;
    const int start = rowptr[d], end = rowptr[d + 1];
    const float erd = er[d * HEADS + h];
    const __half2* __restrict__ feat2 = (const __half2*)feat;   // row stride 64

    float denom = 0.f, ax = 0.f, ay = 0.f;
    for (int chunk = start; chunk < end; chunk += 64) {
        const int cnt = min(64, end - chunk);
        const int idx = chunk + lane;
        const int sv = csr_src[idx < end ? idx : start];
        int i = 0;
        for (; i + 4 <= cnt; i += 4) {
            const int s0 = __shfl(sv, i);
            const int s1 = __shfl(sv, i + 1);
            const int s2 = __shfl(sv, i + 2);
            const int s3 = __shfl(sv, i + 3);
            const float e0 = el[s0 * HEADS + h];
            const float e1 = el[s1 * HEADS + h];
            const float e2 = el[s2 * HEADS + h];
            const float e3 = el[s3 * HEADS + h];
            const __half2 q0 = feat2[(size_t)s0 * 64 + lane];
            const __half2 q1 = feat2[(size_t)s1 * 64 + lane];
            const __half2 q2 = feat2[(size_t)s2 * 64 + lane];
            const __half2 q3 = feat2[(size_t)s3 * 64 + lane];
            float v0 = e0 + erd; v0 = v0 > 0.f ? v0 : NEG_SLOPE * v0;
            float v1 = e1 + erd; v1 = v1 > 0.f ? v1 : NEG_SLOPE * v1;
            float v2 = e2 + erd; v2 = v2 > 0.f ? v2 : NEG_SLOPE * v2;
            float v3 = e3 + erd; v3 = v3 > 0.f ? v3 : NEG_SLOPE * v3;
            const float x0 = __expf(v0);
            const float x1 = __expf(v1);
            const float x2 = __expf(v2);
            const float x3 = __expf(v3);
            const float2 f0 = __half22float2(q0);
            const float2 f1 = __half22float2(q1);
            const float2 f2 = __half22float2(q2);
            const float2 f3 = __half22float2(q3);
            denom += (x0 + x1) + (x2 + x3);
            ax += f0.x * x0 + f1.x * x1 + f2.x * x2 + f3.x * x3;
            ay += f0.y * x0 + f1.y * x1 + f2.y * x2 + f3.y * x3;
        }
        for (; i < cnt; ++i) {
            const int s0 = __shfl(sv, i);
            const float e0 = el[s0 * HEADS + h];
            const __half2 q0 = feat2[(size_t)s0 * 64 + lane];
            float v0 = e0 + erd; v0 = v0 > 0.f ? v0 : NEG_SLOPE * v0;
            const float x0 = __expf(v0);
            const float2 f0 = __half22float2(q0);
            denom += x0;
            ax += f0.x * x0;
            ay += f0.y * x0;
        }
    }
    const float inv = 1.f / fmaxf(denom, 1e-9f);
    const float hx = fmaxf(ax * inv, 0.f);
    const float hy = fmaxf(ay * inv, 0.f);

    if (!FUSE_HEADS) {
        *(float2*)&outh[(size_t)d * HID + lane * 2] = make_float2(hx, hy);
        return;
    }

    float ac[10], af[10];
#pragma unroll
    for (int o = 0; o < 10; ++o) {
        ac[o] = hx * Wc1[(lane * 2) * 10 + o] + hy * Wc1[(lane * 2 + 1) * 10 + o];
        af[o] = hx * Wf1[(lane * 2) * 10 + o] + hy * Wf1[(lane * 2 + 1) * 10 + o];
    }
#pragma unroll
    for (int off = 32; off >= 1; off >>= 1) {
#pragma unroll
        for (int o = 0; o < 10; ++o) {
            ac[o] += __shfl_xor(ac[o], off);
            af[o] += __shfl_xor(af[o], off);
        }
    }
    if (lane == 0) {
        float pc = bc2[0], pf = bf2[0];
#pragma unroll
        for (int o = 0; o < 10; ++o) {
            pc += fmaxf(ac[o] + bc1[o], 0.f) * Wc2[o];
            pf += fmaxf(af[o] + bf1[o], 0.f) * Wf2[o];
        }
        out[d] = pc;
        out[N_NODES + d] = 1.0f / (1.0f + __expf(-pf));
    }
}

extern "C" void kernel_launch(void* const* d_in, const int* in_sizes, int n_in,
                              void* d_out, int out_size, void* d_ws, size_t ws_size,
                              hipStream_t stream) {
    const float* features = (const float*)d_in[0];
    const int*   src      = (const int*)d_in[1];
    const int*   dst      = (const int*)d_in[2];
    const float* W1  = (const float*)d_in[3];
    const float* al1 = (const float*)d_in[4];
    const float* ar1 = (const float*)d_in[5];
    const float* W2  = (const float*)d_in[6];
    const float* al2 = (const float*)d_in[7];
    const float* ar2 = (const float*)d_in[8];
    const float* Wc1 = (const float*)d_in[9];
    const float* bc1 = (const float*)d_in[10];
    const float* Wc2 = (const float*)d_in[11];
    const float* bc2 = (const float*)d_in[12];
    const float* Wf1 = (const float*)d_in[13];
    const float* bf1 = (const float*)d_in[14];
    const float* Wf2 = (const float*)d_in[15];
    const float* bf2 = (const float*)d_in[16];
    float* out = (float*)d_out;

    // workspace layout (float-sized slots; feat uses half of its slot as fp16):
    // feat[128N fp32 slot] | hbuf[128N] | el[4N] | er[4N] | ints...
    float* featslot = (float*)d_ws;
    float* hbuf = featslot + (size_t)N_NODES * HID;
    float* el   = hbuf + (size_t)N_NODES * HID;
    float* er   = el + (size_t)N_NODES * HEADS;
    int* counts    = (int*)(er + (size_t)N_NODES * HEADS);
    int* rowptr    = counts + N_NODES;
    int* cursor    = rowptr + N_NODES + 1;
    int* blockSums = cursor + N_NODES;
    int* csr_src   = blockSums + 256;
    __half* feat   = (__half*)featslot;

    const int nodeWaveBlocks = (N_NODES * 64 + 255) / 256;   // 12500
    const int edgeBlocks     = (N_EDGES + 255) / 256;        // 3907
    const int gemmBlocks     = ((N_NODES + 63) / 64) * 2;    // 1564
    const int scatterBlocks  = SCHUNKS * NPART;              // 2048

    // ---------- CSR build (dst-sorted incidence), reused by both layers ------
    zero_counts<<<NB_SCAN, 256, 0, stream>>>(counts);
    hist_dst<<<edgeBlocks, 256, 0, stream>>>(dst, counts);
    scan_local<<<NB_SCAN, 256, 0, stream>>>(counts, rowptr, blockSums);
    scan_sums<<<1, 256, 0, stream>>>(blockSums);
    add_offsets<<<NB_SCAN, 256, 0, stream>>>(rowptr, blockSums, cursor);
    scatter_csr_part<<<scatterBlocks, 256, 0, stream>>>(src, dst, cursor, csr_src);

    // ---------- layer 1 ----------
    gemm_fused<F_IN><<<gemmBlocks, 256, 0, stream>>>(features, W1, al1, ar1,
                                                     feat, el, er);
    gat_aggregate<false><<<nodeWaveBlocks, 256, 0, stream>>>(
        rowptr, csr_src, el, er, feat, hbuf,
        Wc1, bc1, Wc2, bc2, Wf1, bf1, Wf2, bf2, out);

    // ---------- layer 2 (heads fused into aggregation epilogue) ----------
    gemm_fused<HID><<<gemmBlocks, 256, 0, stream>>>(hbuf, W2, al2, ar2,
                                                    feat, el, er);
    gat_aggregate<true><<<nodeWaveBlocks, 256, 0, stream>>>(
        rowptr, csr_src, el, er, feat, nullptr,
        Wc1, bc1, Wc2, bc2, Wf1, bf1, Wf2, bf2, out);
}